// Round 1
// baseline (122.360 us; speedup 1.0000x reference)
//
#include <hip/hip_runtime.h>
#include <hip/hip_bf16.h>
#include <stdint.h>

// Problem constants
#define S_LEN   4096
#define HIDDEN  1024
#define NHEAD   16
#define NKV     4
#define HD      64
#define WINDOW  512

using short8 = __attribute__((ext_vector_type(8))) short;
using f32x4  = __attribute__((ext_vector_type(4))) float;

// fp32 -> bf16, round-to-nearest-even (inputs are finite randn; no NaN path needed)
__device__ __forceinline__ uint16_t f2bf(float f) {
  uint32_t u = __builtin_bit_cast(uint32_t, f);
  u += 0x7fffu + ((u >> 16) & 1u);
  return (uint16_t)(u >> 16);
}

// async global->LDS, 16B per lane. LDS dest must be wave-uniform base + lane*16.
__device__ __forceinline__ void gld_lds16(void* lds, const void* g) {
  __builtin_amdgcn_global_load_lds(
      (const __attribute__((address_space(1))) char*)g,
      (__attribute__((address_space(3))) char*)lds, 16, 0, 0);
}

// ---------------------------------------------------------------------------
// Kernel 1: pack x, wq|wk|wv (concat rows), wo to bf16
// ---------------------------------------------------------------------------
__global__ __launch_bounds__(256) void k_tobf16(
    const float* __restrict__ x, const float* __restrict__ wq,
    const float* __restrict__ wk, const float* __restrict__ wv,
    const float* __restrict__ wo,
    uint16_t* __restrict__ xb, uint16_t* __restrict__ wqkvb,
    uint16_t* __restrict__ wob) {
  int i = blockIdx.x * 256 + threadIdx.x;  // one float4 per thread, exact grid
  const float4* src; uint16_t* dst; int off;
  if (i < 1048576)      { src = (const float4*)x;  dst = xb;                off = i; }
  else if (i < 1310720) { src = (const float4*)wq; dst = wqkvb;             off = i - 1048576; }
  else if (i < 1376256) { src = (const float4*)wk; dst = wqkvb + 1024*1024; off = i - 1310720; }
  else if (i < 1441792) { src = (const float4*)wv; dst = wqkvb + 1280*1024; off = i - 1376256; }
  else                  { src = (const float4*)wo; dst = wob;               off = i - 1441792; }
  float4 v = src[off];
  ushort4 o = { f2bf(v.x), f2bf(v.y), f2bf(v.z), f2bf(v.w) };
  *(ushort4*)(dst + (size_t)off * 4) = o;
}

// ---------------------------------------------------------------------------
// Kernel 2/5: C[M][N] = A[M][K] * B[N][K]^T, bf16 in, fp32 out.
// m97 structure: 128x128 tile, BK=64, 4 waves (2x2), global_load_lds width 16.
// ---------------------------------------------------------------------------
__global__ __launch_bounds__(256) void k_gemm_bf16(
    const uint16_t* __restrict__ A, const uint16_t* __restrict__ B,
    float* __restrict__ C, int N, int K) {
  __shared__ uint16_t As[128 * 64];
  __shared__ uint16_t Bs[128 * 64];
  const int t = threadIdx.x;
  const int lane = t & 63, w = t >> 6;
  const int wr = w >> 1, wc = w & 1;
  const int l16 = lane & 15, lg = lane >> 4;
  const int bm = blockIdx.x, bn = blockIdx.y;
  const uint16_t* Ab = A + (size_t)bm * 128 * K;
  const uint16_t* Bb = B + (size_t)bn * 128 * K;
  f32x4 acc[4][4] = {};
  for (int k0 = 0; k0 < K; k0 += 64) {
    __syncthreads();  // previous tile consumed
#pragma unroll
    for (int it = 0; it < 4; ++it) {
      int idx = it * 256 + t;
      int row = idx >> 3, c8 = (idx & 7) << 3;
      gld_lds16(&As[idx * 8], Ab + (size_t)row * K + k0 + c8);
      gld_lds16(&Bs[idx * 8], Bb + (size_t)row * K + k0 + c8);
    }
    __syncthreads();  // drains vmcnt (compiler emits full waitcnt before barrier)
#pragma unroll
    for (int kk = 0; kk < 2; ++kk) {
      short8 af[4], bq[4];
#pragma unroll
      for (int i = 0; i < 4; ++i) {
        af[i] = *(const short8*)&As[(wr * 64 + i * 16 + l16) * 64 + kk * 32 + lg * 8];
        bq[i] = *(const short8*)&Bs[(wc * 64 + i * 16 + l16) * 64 + kk * 32 + lg * 8];
      }
#pragma unroll
      for (int i = 0; i < 4; ++i)
#pragma unroll
        for (int j = 0; j < 4; ++j)
          acc[i][j] = __builtin_amdgcn_mfma_f32_16x16x32_bf16(af[i], bq[j], acc[i][j], 0, 0, 0);
    }
  }
  // epilogue: D row = (lane>>4)*4+reg, col = lane&15 (verified m89 mapping)
#pragma unroll
  for (int i = 0; i < 4; ++i) {
    int row0 = bm * 128 + wr * 64 + i * 16 + lg * 4;
#pragma unroll
    for (int j = 0; j < 4; ++j) {
      int col = bn * 128 + wc * 64 + j * 16 + l16;
#pragma unroll
      for (int r = 0; r < 4; ++r)
        C[(size_t)(row0 + r) * N + col] = acc[i][j][r];
    }
  }
}

// ---------------------------------------------------------------------------
// Kernel 3: per-head RMSNorm + RoPE + layout/cast.
// One wave per (s, head-global) pair; lane = d in [0,64).
//   hg in [0,16):  q head -> norm+rope, *0.125 (fold 1/sqrt(D)), q[s][hg*64+d]
//   hg in [16,20): k head -> norm+rope, k[kv][s][d]
//   hg in [20,24): v head -> cast only, vT[kv][d][s]
// ---------------------------------------------------------------------------
__global__ __launch_bounds__(256) void k_normrope(
    const float* __restrict__ qkv, const float* __restrict__ cosb,
    const float* __restrict__ sinb, const float* __restrict__ qw,
    const float* __restrict__ kw,
    uint16_t* __restrict__ qout, uint16_t* __restrict__ kout,
    uint16_t* __restrict__ vtout) {
  int gw = blockIdx.x * 4 + (threadIdx.x >> 6);
  int lane = threadIdx.x & 63;
  int s = gw / 24, hg = gw - s * 24;
  float v = qkv[(size_t)s * 1536 + hg * 64 + lane];
  if (hg >= 20) {
    int kvh = hg - 20;
    vtout[(size_t)(kvh * 64 + lane) * S_LEN + s] = f2bf(v);
    return;
  }
  float ss = v * v;
  ss += __shfl_xor(ss, 1);  ss += __shfl_xor(ss, 2);  ss += __shfl_xor(ss, 4);
  ss += __shfl_xor(ss, 8);  ss += __shfl_xor(ss, 16); ss += __shfl_xor(ss, 32);
  float inv = rsqrtf(ss * (1.0f / 64.0f) + 1e-5f);
  float wgt = (hg < 16) ? qw[lane] : kw[lane];
  float qn = v * inv * wgt;
  float partner = __shfl_xor(qn, 32);
  float rot = (lane < 32) ? -partner : partner;   // rotate_half
  float o = qn * cosb[s * 64 + lane] + rot * sinb[s * 64 + lane];
  if (hg < 16) {
    qout[(size_t)s * HIDDEN + hg * 64 + lane] = f2bf(o * 0.125f);
  } else {
    int kvh = hg - 16;
    kout[((size_t)kvh * S_LEN + s) * 64 + lane] = f2bf(o);
  }
}

// ---------------------------------------------------------------------------
// Kernel 4: sliding-window flash attention with sink.
// Grid (S/64, H). 4 waves/block; wave w owns 16 q-rows. 64-key tiles.
// ---------------------------------------------------------------------------
__global__ __launch_bounds__(256) void k_attn(
    const uint16_t* __restrict__ qb,   // [S][HIDDEN], pre-scaled by 0.125
    const uint16_t* __restrict__ kb,   // [KV][S][64]
    const uint16_t* __restrict__ vtb,  // [KV][64][S]
    const float* __restrict__ sinks,
    uint16_t* __restrict__ ao) {       // [S][HIDDEN]
  __shared__ uint16_t Kl[64][72];      // +8 pad: row stride 144B -> 2-way-free
  __shared__ uint16_t Vl[64][72];      // V^T tile: [d][key]
  __shared__ uint16_t Pl[4][16][72];   // per-wave P scratch
  const int q0 = blockIdx.x * 64;
  const int h = blockIdx.y;
  const int kvh = h >> 2;
  const int t = threadIdx.x;
  const int lane = t & 63, w = t >> 6;
  const int l16 = lane & 15, lg = lane >> 4;
  const int qrow_base = q0 + w * 16 + lg * 4;

  // hoist Q fragments (A operand: row = lane&15, k = (lane>>4)*8..+7)
  short8 aq0, aq1;
  {
    const uint16_t* qp = qb + (size_t)(q0 + w * 16 + l16) * HIDDEN + h * 64 + lg * 8;
    aq0 = *(const short8*)qp;
    aq1 = *(const short8*)(qp + 32);
  }
  float m[4]    = {-1e30f, -1e30f, -1e30f, -1e30f};
  float lsum[4] = {0.f, 0.f, 0.f, 0.f};
  f32x4 acc[4] = {};

  int kstart = q0 - WINDOW;   // first 64-aligned tile that can contain i-511
  if (kstart < 0) kstart = 0;
  for (int k0 = kstart; k0 <= q0; k0 += 64) {
    __syncthreads();  // previous K/V tile fully consumed
    // reg-stage K and V^T tiles (padded LDS, so no global_load_lds)
#pragma unroll
    for (int it = 0; it < 2; ++it) {
      int j = it * 256 + t;
      int row = j >> 3, c8 = (j & 7) << 3;
      *(short8*)&Kl[row][c8] =
          *(const short8*)(kb + ((size_t)kvh * S_LEN + k0 + row) * 64 + c8);
      *(short8*)&Vl[row][c8] =
          *(const short8*)(vtb + ((size_t)kvh * 64 + row) * S_LEN + k0 + c8);
    }
    __syncthreads();

    // S = Q K^T (pre-scaled). 4 key-subtiles x (K=64 -> 2 mfma)
    f32x4 st[4] = {};
#pragma unroll
    for (int c = 0; c < 4; ++c) {
      short8 bk0 = *(const short8*)&Kl[c * 16 + l16][lg * 8];
      short8 bk1 = *(const short8*)&Kl[c * 16 + l16][32 + lg * 8];
      st[c] = __builtin_amdgcn_mfma_f32_16x16x32_bf16(aq0, bk0, st[c], 0, 0, 0);
      st[c] = __builtin_amdgcn_mfma_f32_16x16x32_bf16(aq1, bk1, st[c], 0, 0, 0);
    }

    // mask + online softmax. D layout: row=(lane>>4)*4+r, col=lane&15.
    float pv[4][4];
#pragma unroll
    for (int c = 0; c < 4; ++c) {
      int key = k0 + c * 16 + l16;
#pragma unroll
      for (int r = 0; r < 4; ++r) {
        int row = qrow_base + r;
        bool ok = (key <= row) && (key + WINDOW > row);
        pv[c][r] = ok ? st[c][r] : -1e30f;
      }
    }
#pragma unroll
    for (int r = 0; r < 4; ++r) {
      float rmax = fmaxf(fmaxf(pv[0][r], pv[1][r]), fmaxf(pv[2][r], pv[3][r]));
      rmax = fmaxf(rmax, __shfl_xor(rmax, 1));
      rmax = fmaxf(rmax, __shfl_xor(rmax, 2));
      rmax = fmaxf(rmax, __shfl_xor(rmax, 4));
      rmax = fmaxf(rmax, __shfl_xor(rmax, 8));
      float mn = fmaxf(m[r], rmax);
      float sc = __expf(m[r] - mn);
      m[r] = mn;
      float rs = 0.f;
#pragma unroll
      for (int c = 0; c < 4; ++c) {
        // guard: fully-masked rows (possible in first tile) must produce 0, not exp(0)
        float e = (pv[c][r] > -1e29f) ? __expf(pv[c][r] - mn) : 0.f;
        pv[c][r] = e;
        rs += e;
      }
      rs += __shfl_xor(rs, 1); rs += __shfl_xor(rs, 2);
      rs += __shfl_xor(rs, 4); rs += __shfl_xor(rs, 8);
      lsum[r] = lsum[r] * sc + rs;
#pragma unroll
      for (int dt = 0; dt < 4; ++dt) acc[dt][r] *= sc;
    }

    // P -> per-wave LDS (layout [qsub][key]), then read as PV A-operand
#pragma unroll
    for (int c = 0; c < 4; ++c)
#pragma unroll
      for (int r = 0; r < 4; ++r)
        Pl[w][lg * 4 + r][c * 16 + l16] = f2bf(pv[c][r]);
    asm volatile("s_waitcnt lgkmcnt(0)" ::: "memory");
    short8 pa0 = *(const short8*)&Pl[w][l16][lg * 8];
    short8 pa1 = *(const short8*)&Pl[w][l16][32 + lg * 8];
#pragma unroll
    for (int dt = 0; dt < 4; ++dt) {
      short8 bv0 = *(const short8*)&Vl[dt * 16 + l16][lg * 8];
      short8 bv1 = *(const short8*)&Vl[dt * 16 + l16][32 + lg * 8];
      acc[dt] = __builtin_amdgcn_mfma_f32_16x16x32_bf16(pa0, bv0, acc[dt], 0, 0, 0);
      acc[dt] = __builtin_amdgcn_mfma_f32_16x16x32_bf16(pa1, bv1, acc[dt], 0, 0, 0);
    }
  }

  // finalize: sink joins the denominator only
  float sk = sinks[h];
#pragma unroll
  for (int r = 0; r < 4; ++r) {
    float rd = 1.0f / (lsum[r] + __expf(sk - m[r]));
#pragma unroll
    for (int dt = 0; dt < 4; ++dt)
      ao[(size_t)(qrow_base + r) * HIDDEN + h * 64 + dt * 16 + l16] =
          f2bf(acc[dt][r] * rd);
  }
}

// ---------------------------------------------------------------------------
// Launch. Workspace layout (needs ~57 MB of d_ws):
//   [0,8M)    xb      bf16 x            [4096][1024]
//   [8,11M)   wqkvb   bf16 wq|wk|wv     [1536][1024]
//   [11,13M)  wob     bf16 wo           [1024][1024]
//   [13,37M)  qkv     f32 projections   [4096][1536]
//   [37,45M)  qsc     bf16 q (scaled)   [4096][1024]
//   [45,47M)  kbf     bf16 k            [4][4096][64]
//   [47,49M)  vtb     bf16 v^T          [4][64][4096]
//   [49,57M)  aob     bf16 attn out     [4096][1024]
// ---------------------------------------------------------------------------
extern "C" void kernel_launch(void* const* d_in, const int* in_sizes, int n_in,
                              void* d_out, int out_size, void* d_ws, size_t ws_size,
                              hipStream_t stream) {
  const float* x     = (const float*)d_in[0];
  const float* cosb  = (const float*)d_in[1];
  const float* sinb  = (const float*)d_in[2];
  const float* wq    = (const float*)d_in[3];
  const float* wk    = (const float*)d_in[4];
  const float* wv    = (const float*)d_in[5];
  const float* wo    = (const float*)d_in[6];
  const float* qnw   = (const float*)d_in[7];
  const float* knw   = (const float*)d_in[8];
  const float* sinks = (const float*)d_in[9];
  float* out = (float*)d_out;

  char* ws = (char*)d_ws;
  uint16_t* xb    = (uint16_t*)(ws);
  uint16_t* wqkvb = (uint16_t*)(ws + (8ll  << 20));
  uint16_t* wob   = (uint16_t*)(ws + (11ll << 20));
  float*    qkv   = (float*)   (ws + (13ll << 20));
  uint16_t* qsc   = (uint16_t*)(ws + (37ll << 20));
  uint16_t* kbf   = (uint16_t*)(ws + (45ll << 20));
  uint16_t* vtb   = (uint16_t*)(ws + (47ll << 20));
  uint16_t* aob   = (uint16_t*)(ws + (49ll << 20));

  k_tobf16  <<<6656, 256, 0, stream>>>(x, wq, wk, wv, wo, xb, wqkvb, wob);
  k_gemm_bf16<<<dim3(32, 12), 256, 0, stream>>>(xb, wqkvb, qkv, 1536, 1024);
  k_normrope<<<24576, 256, 0, stream>>>(qkv, cosb, sinb, qnw, knw, qsc, kbf, vtb);
  k_attn    <<<dim3(64, 16), 256, 0, stream>>>(qsc, kbf, vtb, sinks, aob);
  k_gemm_bf16<<<dim3(32, 8), 256, 0, stream>>>(aob, wob, out, 1024, 1024);
}

// Round 2
// 104.482 us; speedup vs baseline: 1.1711x; 1.1711x over previous
//
#include <hip/hip_runtime.h>
#include <hip/hip_bf16.h>
#include <stdint.h>

// Problem constants
#define S_LEN   4096
#define HIDDEN  1024
#define NHEAD   16
#define NKV     4
#define HD      64
#define WINDOW  512
#define L2E     1.4426950408889634f

using short8 = __attribute__((ext_vector_type(8))) short;
using f32x4  = __attribute__((ext_vector_type(4))) float;

// fp32 -> bf16, round-to-nearest-even
__device__ __forceinline__ uint16_t f2bf(float f) {
  uint32_t u = __builtin_bit_cast(uint32_t, f);
  u += 0x7fffu + ((u >> 16) & 1u);
  return (uint16_t)(u >> 16);
}
// cheap round-to-nearest (ties up) — used on P only (bias ~2^-17, negligible)
__device__ __forceinline__ uint16_t f2bf_rn(float f) {
  uint32_t u = __builtin_bit_cast(uint32_t, f);
  return (uint16_t)((u + 0x8000u) >> 16);
}

// async global->LDS, 16B per lane. LDS dest must be wave-uniform base + lane*16.
__device__ __forceinline__ void gld_lds16(void* lds, const void* g) {
  __builtin_amdgcn_global_load_lds(
      (const __attribute__((address_space(1))) char*)g,
      (__attribute__((address_space(3))) char*)lds, 16, 0, 0);
}

// ---------------------------------------------------------------------------
// Kernel 1: pack x, wq|wk|wv (concat rows), wo to bf16
// ---------------------------------------------------------------------------
__global__ __launch_bounds__(256) void k_tobf16(
    const float* __restrict__ x, const float* __restrict__ wq,
    const float* __restrict__ wk, const float* __restrict__ wv,
    const float* __restrict__ wo,
    uint16_t* __restrict__ xb, uint16_t* __restrict__ wqkvb,
    uint16_t* __restrict__ wob) {
  int i = blockIdx.x * 256 + threadIdx.x;  // one float4 per thread, exact grid
  const float4* src; uint16_t* dst; int off;
  if (i < 1048576)      { src = (const float4*)x;  dst = xb;                off = i; }
  else if (i < 1310720) { src = (const float4*)wq; dst = wqkvb;             off = i - 1048576; }
  else if (i < 1376256) { src = (const float4*)wk; dst = wqkvb + 1024*1024; off = i - 1310720; }
  else if (i < 1441792) { src = (const float4*)wv; dst = wqkvb + 1280*1024; off = i - 1376256; }
  else                  { src = (const float4*)wo; dst = wob;               off = i - 1441792; }
  float4 v = src[off];
  ushort4 o = { f2bf(v.x), f2bf(v.y), f2bf(v.z), f2bf(v.w) };
  *(ushort4*)(dst + (size_t)off * 4) = o;
}

// ---------------------------------------------------------------------------
// Kernel 2/5: C[M][N] = A[M][K] * B[N][K]^T, bf16 in, fp32 out.
// m97 structure: 128x128 tile, BK=64, 4 waves (2x2), global_load_lds width 16.
// ---------------------------------------------------------------------------
__global__ __launch_bounds__(256) void k_gemm_bf16(
    const uint16_t* __restrict__ A, const uint16_t* __restrict__ B,
    float* __restrict__ C, int N, int K) {
  __shared__ uint16_t As[128 * 64];
  __shared__ uint16_t Bs[128 * 64];
  const int t = threadIdx.x;
  const int lane = t & 63, w = t >> 6;
  const int wr = w >> 1, wc = w & 1;
  const int l16 = lane & 15, lg = lane >> 4;
  const int bm = blockIdx.x, bn = blockIdx.y;
  const uint16_t* Ab = A + (size_t)bm * 128 * K;
  const uint16_t* Bb = B + (size_t)bn * 128 * K;
  f32x4 acc[4][4] = {};
  for (int k0 = 0; k0 < K; k0 += 64) {
    __syncthreads();  // previous tile consumed
#pragma unroll
    for (int it = 0; it < 4; ++it) {
      int idx = it * 256 + t;
      int row = idx >> 3, c8 = (idx & 7) << 3;
      gld_lds16(&As[idx * 8], Ab + (size_t)row * K + k0 + c8);
      gld_lds16(&Bs[idx * 8], Bb + (size_t)row * K + k0 + c8);
    }
    __syncthreads();  // drains vmcnt (compiler emits full waitcnt before barrier)
#pragma unroll
    for (int kk = 0; kk < 2; ++kk) {
      short8 af[4], bq[4];
#pragma unroll
      for (int i = 0; i < 4; ++i) {
        af[i] = *(const short8*)&As[(wr * 64 + i * 16 + l16) * 64 + kk * 32 + lg * 8];
        bq[i] = *(const short8*)&Bs[(wc * 64 + i * 16 + l16) * 64 + kk * 32 + lg * 8];
      }
#pragma unroll
      for (int i = 0; i < 4; ++i)
#pragma unroll
        for (int j = 0; j < 4; ++j)
          acc[i][j] = __builtin_amdgcn_mfma_f32_16x16x32_bf16(af[i], bq[j], acc[i][j], 0, 0, 0);
    }
  }
  // epilogue: D row = (lane>>4)*4+reg, col = lane&15 (verified m89 mapping)
#pragma unroll
  for (int i = 0; i < 4; ++i) {
    int row0 = bm * 128 + wr * 64 + i * 16 + lg * 4;
#pragma unroll
    for (int j = 0; j < 4; ++j) {
      int col = bn * 128 + wc * 64 + j * 16 + l16;
#pragma unroll
      for (int r = 0; r < 4; ++r)
        C[(size_t)(row0 + r) * N + col] = acc[i][j][r];
    }
  }
}

// ---------------------------------------------------------------------------
// Kernel 3: per-head RMSNorm + RoPE + layout/cast.
//   q heads: norm+rope, * (0.125*log2e)  -> scores come out in log2 domain
//   k heads: norm+rope -> k[kv][s][d]
//   v heads: cast only -> vT[kv][d][s]
// ---------------------------------------------------------------------------
__global__ __launch_bounds__(256) void k_normrope(
    const float* __restrict__ qkv, const float* __restrict__ cosb,
    const float* __restrict__ sinb, const float* __restrict__ qw,
    const float* __restrict__ kw,
    uint16_t* __restrict__ qout, uint16_t* __restrict__ kout,
    uint16_t* __restrict__ vtout) {
  int gw = blockIdx.x * 4 + (threadIdx.x >> 6);
  int lane = threadIdx.x & 63;
  int s = gw / 24, hg = gw - s * 24;
  float v = qkv[(size_t)s * 1536 + hg * 64 + lane];
  if (hg >= 20) {
    int kvh = hg - 20;
    vtout[(size_t)(kvh * 64 + lane) * S_LEN + s] = f2bf(v);
    return;
  }
  float ss = v * v;
  ss += __shfl_xor(ss, 1);  ss += __shfl_xor(ss, 2);  ss += __shfl_xor(ss, 4);
  ss += __shfl_xor(ss, 8);  ss += __shfl_xor(ss, 16); ss += __shfl_xor(ss, 32);
  float inv = rsqrtf(ss * (1.0f / 64.0f) + 1e-5f);
  float wgt = (hg < 16) ? qw[lane] : kw[lane];
  float qn = v * inv * wgt;
  float partner = __shfl_xor(qn, 32);
  float rot = (lane < 32) ? -partner : partner;   // rotate_half
  float o = qn * cosb[s * 64 + lane] + rot * sinb[s * 64 + lane];
  if (hg < 16) {
    qout[(size_t)s * HIDDEN + hg * 64 + lane] = f2bf(o * (0.125f * L2E));
  } else {
    int kvh = hg - 16;
    kout[((size_t)kvh * S_LEN + s) * 64 + lane] = f2bf(o);
  }
}

// ---------------------------------------------------------------------------
// Kernel 4: sliding-window flash attention with sink.
// Grid (S/64, 8). 512 threads = 8 waves; block covers one 64-row q-tile x
// TWO heads of the same kv group (K/V staged once, shared by all 8 waves).
// Wave w: head (w>>2), q-subtile (w&3) [16 rows].
// Fixed-max softmax (scores bounded by ±8·log2e after prescale): p=exp2(s),
// no online max, no acc rescale. Masks only on the 2 edge tiles.
// ---------------------------------------------------------------------------
__global__ __launch_bounds__(512) void k_attn(
    const uint16_t* __restrict__ qb,   // [S][HIDDEN], pre-scaled by 0.125*log2e
    const uint16_t* __restrict__ kb,   // [KV][S][64]
    const uint16_t* __restrict__ vtb,  // [KV][64][S]
    const float* __restrict__ sinks,
    uint16_t* __restrict__ ao) {       // [S][HIDDEN]
  __shared__ uint16_t Kl[64][72];      // +8 pad
  __shared__ uint16_t Vl[64][72];      // V^T tile: [d][key]
  __shared__ uint16_t Pl[8][16][72];   // per-wave P scratch
  const int q0 = (63 - blockIdx.x) * 64;   // long blocks (high q0) first
  const int hp = blockIdx.y;               // head-pair id 0..7
  const int kvh = hp >> 1;
  const int t = threadIdx.x;
  const int lane = t & 63, w = t >> 6;
  const int h = kvh * 4 + (hp & 1) * 2 + (w >> 2);
  const int wq = w & 3;
  const int l16 = lane & 15, lg = lane >> 4;
  const int qrow_base = q0 + wq * 16 + lg * 4;

  // hoist Q fragments (A operand: row = lane&15, k = (lane>>4)*8..+7)
  short8 aq0, aq1;
  {
    const uint16_t* qp = qb + (size_t)(q0 + wq * 16 + l16) * HIDDEN + h * 64 + lg * 8;
    aq0 = *(const short8*)qp;
    aq1 = *(const short8*)(qp + 32);
  }
  float lsum[4] = {0.f, 0.f, 0.f, 0.f};
  f32x4 acc[4] = {};

  int kstart = q0 - WINDOW;
  if (kstart < 0) kstart = 0;
  for (int k0 = kstart; k0 <= q0; k0 += 64) {
    __syncthreads();  // previous K/V tile fully consumed
    {   // reg-stage K and V^T tiles: 512 threads -> one short8 each per array
      int row = t >> 3, c8 = (t & 7) << 3;
      *(short8*)&Kl[row][c8] =
          *(const short8*)(kb + ((size_t)kvh * S_LEN + k0 + row) * 64 + c8);
      *(short8*)&Vl[row][c8] =
          *(const short8*)(vtb + ((size_t)kvh * 64 + row) * S_LEN + k0 + c8);
    }
    __syncthreads();

    // S = Q K^T (pre-scaled, log2 domain). 4 key-subtiles x (K=64 -> 2 mfma)
    f32x4 st[4] = {};
#pragma unroll
    for (int c = 0; c < 4; ++c) {
      short8 bk0 = *(const short8*)&Kl[c * 16 + l16][lg * 8];
      short8 bk1 = *(const short8*)&Kl[c * 16 + l16][32 + lg * 8];
      st[c] = __builtin_amdgcn_mfma_f32_16x16x32_bf16(aq0, bk0, st[c], 0, 0, 0);
      st[c] = __builtin_amdgcn_mfma_f32_16x16x32_bf16(aq1, bk1, st[c], 0, 0, 0);
    }

    // p = exp2(s); fixed max (scores bounded), mask only on edge tiles.
    // D layout: row=(lane>>4)*4+r, col=lane&15 -> key = k0+c*16+l16.
    float p[4][4];
    if (k0 == q0 || k0 == q0 - WINDOW) {
#pragma unroll
      for (int c = 0; c < 4; ++c) {
        int key = k0 + c * 16 + l16;
#pragma unroll
        for (int r = 0; r < 4; ++r) {
          int row = qrow_base + r;
          bool ok = (key <= row) && (key + WINDOW > row);
          p[c][r] = ok ? exp2f(st[c][r]) : 0.f;
        }
      }
    } else {
#pragma unroll
      for (int c = 0; c < 4; ++c)
#pragma unroll
        for (int r = 0; r < 4; ++r)
          p[c][r] = exp2f(st[c][r]);
    }
#pragma unroll
    for (int r = 0; r < 4; ++r)
      lsum[r] += (p[0][r] + p[1][r]) + (p[2][r] + p[3][r]);

    // P -> per-wave LDS (layout [qsub][key]), then read as PV A-operand
#pragma unroll
    for (int c = 0; c < 4; ++c)
#pragma unroll
      for (int r = 0; r < 4; ++r)
        Pl[w][lg * 4 + r][c * 16 + l16] = f2bf_rn(p[c][r]);
    asm volatile("s_waitcnt lgkmcnt(0)" ::: "memory");
    short8 pa0 = *(const short8*)&Pl[w][l16][lg * 8];
    short8 pa1 = *(const short8*)&Pl[w][l16][32 + lg * 8];
#pragma unroll
    for (int dt = 0; dt < 4; ++dt) {
      short8 bv0 = *(const short8*)&Vl[dt * 16 + l16][lg * 8];
      short8 bv1 = *(const short8*)&Vl[dt * 16 + l16][32 + lg * 8];
      acc[dt] = __builtin_amdgcn_mfma_f32_16x16x32_bf16(pa0, bv0, acc[dt], 0, 0, 0);
      acc[dt] = __builtin_amdgcn_mfma_f32_16x16x32_bf16(pa1, bv1, acc[dt], 0, 0, 0);
    }
  }

  // finalize: reduce per-lane partial sums over the 16 key-columns, add sink
#pragma unroll
  for (int r = 0; r < 4; ++r) {
    lsum[r] += __shfl_xor(lsum[r], 1);
    lsum[r] += __shfl_xor(lsum[r], 2);
    lsum[r] += __shfl_xor(lsum[r], 4);
    lsum[r] += __shfl_xor(lsum[r], 8);
  }
  float sk = exp2f(sinks[h] * L2E);
#pragma unroll
  for (int r = 0; r < 4; ++r) {
    float rd = 1.0f / (lsum[r] + sk);
#pragma unroll
    for (int dt = 0; dt < 4; ++dt)
      ao[(size_t)(qrow_base + r) * HIDDEN + h * 64 + dt * 16 + l16] =
          f2bf(acc[dt][r] * rd);
  }
}

// ---------------------------------------------------------------------------
// Launch. Workspace layout (needs ~57 MB of d_ws):
//   [0,8M)    xb      bf16 x            [4096][1024]
//   [8,11M)   wqkvb   bf16 wq|wk|wv     [1536][1024]
//   [11,13M)  wob     bf16 wo           [1024][1024]
//   [13,37M)  qkv     f32 projections   [4096][1536]
//   [37,45M)  qsc     bf16 q (scaled)   [4096][1024]
//   [45,47M)  kbf     bf16 k            [4][4096][64]
//   [47,49M)  vtb     bf16 v^T          [4][64][4096]
//   [49,57M)  aob     bf16 attn out     [4096][1024]
// ---------------------------------------------------------------------------
extern "C" void kernel_launch(void* const* d_in, const int* in_sizes, int n_in,
                              void* d_out, int out_size, void* d_ws, size_t ws_size,
                              hipStream_t stream) {
  const float* x     = (const float*)d_in[0];
  const float* cosb  = (const float*)d_in[1];
  const float* sinb  = (const float*)d_in[2];
  const float* wq    = (const float*)d_in[3];
  const float* wk    = (const float*)d_in[4];
  const float* wv    = (const float*)d_in[5];
  const float* wo    = (const float*)d_in[6];
  const float* qnw   = (const float*)d_in[7];
  const float* knw   = (const float*)d_in[8];
  const float* sinks = (const float*)d_in[9];
  float* out = (float*)d_out;

  char* ws = (char*)d_ws;
  uint16_t* xb    = (uint16_t*)(ws);
  uint16_t* wqkvb = (uint16_t*)(ws + (8ll  << 20));
  uint16_t* wob   = (uint16_t*)(ws + (11ll << 20));
  float*    qkv   = (float*)   (ws + (13ll << 20));
  uint16_t* qsc   = (uint16_t*)(ws + (37ll << 20));
  uint16_t* kbf   = (uint16_t*)(ws + (45ll << 20));
  uint16_t* vtb   = (uint16_t*)(ws + (47ll << 20));
  uint16_t* aob   = (uint16_t*)(ws + (49ll << 20));

  k_tobf16  <<<6656, 256, 0, stream>>>(x, wq, wk, wv, wo, xb, wqkvb, wob);
  k_gemm_bf16<<<dim3(32, 12), 256, 0, stream>>>(xb, wqkvb, qkv, 1536, 1024);
  k_normrope<<<24576, 256, 0, stream>>>(qkv, cosb, sinb, qnw, knw, qsc, kbf, vtb);
  k_attn    <<<dim3(64, 8), 512, 0, stream>>>(qsc, kbf, vtb, sinks, aob);
  k_gemm_bf16<<<dim3(32, 8), 256, 0, stream>>>(aob, wob, out, 1024, 1024);
}

// Round 3
// 90.385 us; speedup vs baseline: 1.3538x; 1.1560x over previous
//
#include <hip/hip_runtime.h>
#include <hip/hip_bf16.h>
#include <stdint.h>

// Problem constants
#define S_LEN   4096
#define HIDDEN  1024
#define NHEAD   16
#define NKV     4
#define HD      64
#define WINDOW  512
#define L2E     1.4426950408889634f
#define QSCALE  (0.125f * L2E)

using short8 = __attribute__((ext_vector_type(8))) short;
using f32x4  = __attribute__((ext_vector_type(4))) float;

// fp32 -> bf16, round-to-nearest-even
__device__ __forceinline__ uint16_t f2bf(float f) {
  uint32_t u = __builtin_bit_cast(uint32_t, f);
  u += 0x7fffu + ((u >> 16) & 1u);
  return (uint16_t)(u >> 16);
}
// round-to-nearest (ties up) — P values only (all >=0, bias ~2^-17)
__device__ __forceinline__ uint16_t f2bf_rn(float f) {
  uint32_t u = __builtin_bit_cast(uint32_t, f);
  return (uint16_t)((u + 0x8000u) >> 16);
}
__device__ __forceinline__ uint32_t pk2(float a, float b) {
  return (uint32_t)f2bf_rn(a) | ((uint32_t)f2bf_rn(b) << 16);
}

// async global->LDS, 16B per lane. LDS dest must be wave-uniform base + lane*16.
__device__ __forceinline__ void gld_lds16(void* lds, const void* g) {
  __builtin_amdgcn_global_load_lds(
      (const __attribute__((address_space(1))) char*)g,
      (__attribute__((address_space(3))) char*)lds, 16, 0, 0);
}

// ---------------------------------------------------------------------------
// Kernel 1: pack x, wq|wk|wv (concat rows), wo to bf16
// ---------------------------------------------------------------------------
__global__ __launch_bounds__(256) void k_tobf16(
    const float* __restrict__ x, const float* __restrict__ wq,
    const float* __restrict__ wk, const float* __restrict__ wv,
    const float* __restrict__ wo,
    uint16_t* __restrict__ xb, uint16_t* __restrict__ wqkvb,
    uint16_t* __restrict__ wob) {
  int i = blockIdx.x * 256 + threadIdx.x;  // one float4 per thread, exact grid
  const float4* src; uint16_t* dst; int off;
  if (i < 1048576)      { src = (const float4*)x;  dst = xb;                off = i; }
  else if (i < 1310720) { src = (const float4*)wq; dst = wqkvb;             off = i - 1048576; }
  else if (i < 1376256) { src = (const float4*)wk; dst = wqkvb + 1024*1024; off = i - 1310720; }
  else if (i < 1441792) { src = (const float4*)wv; dst = wqkvb + 1280*1024; off = i - 1376256; }
  else                  { src = (const float4*)wo; dst = wob;               off = i - 1441792; }
  float4 v = src[off];
  ushort4 o = { f2bf(v.x), f2bf(v.y), f2bf(v.z), f2bf(v.w) };
  *(ushort4*)(dst + (size_t)off * 4) = o;
}

// ---------------------------------------------------------------------------
// Kernel 2: QKV GEMM with fused RMSNorm + RoPE + cast + layout epilogue.
// A = xb [4096][1024], B = wqkvb [1536][1024] (rows = q|k|v heads, 64-aligned).
// Each wave's 64-col half-tile is exactly ONE head:
//   hg = bn*2+wc: [0,16) q-head -> norm+rope, * QSCALE, qout[s][hg*64+d]
//                 [16,20) k-head -> norm+rope, kout[kv][s][d]
//                 [20,24) v-head -> cast, vtout[kv][d][s] (8B vector stores)
// Norm: sum-of-squares = 4 in-lane squares + shfl_xor{1,2,4,8} (16-group).
// RoPE partner d+-32 = same lane, fragment j+-2 (in-register).
// ---------------------------------------------------------------------------
__global__ __launch_bounds__(256) void k_gemm_qkv(
    const uint16_t* __restrict__ A, const uint16_t* __restrict__ B,
    const float* __restrict__ cosb, const float* __restrict__ sinb,
    const float* __restrict__ qw, const float* __restrict__ kw,
    uint16_t* __restrict__ qout, uint16_t* __restrict__ kout,
    uint16_t* __restrict__ vtout) {
  __shared__ uint16_t As[128 * 64];
  __shared__ uint16_t Bs[128 * 64];
  const int K = 1024;
  const int t = threadIdx.x;
  const int lane = t & 63, w = t >> 6;
  const int wr = w >> 1, wc = w & 1;
  const int l16 = lane & 15, lg = lane >> 4;
  const int bm = blockIdx.x, bn = blockIdx.y;
  const uint16_t* Ab = A + (size_t)bm * 128 * K;
  const uint16_t* Bb = B + (size_t)bn * 128 * K;
  f32x4 acc[4][4] = {};
  for (int k0 = 0; k0 < K; k0 += 64) {
    __syncthreads();
#pragma unroll
    for (int it = 0; it < 4; ++it) {
      int idx = it * 256 + t;
      int row = idx >> 3, c8 = (idx & 7) << 3;
      gld_lds16(&As[idx * 8], Ab + (size_t)row * K + k0 + c8);
      gld_lds16(&Bs[idx * 8], Bb + (size_t)row * K + k0 + c8);
    }
    __syncthreads();
#pragma unroll
    for (int kk = 0; kk < 2; ++kk) {
      short8 af[4], bq[4];
#pragma unroll
      for (int i = 0; i < 4; ++i) {
        af[i] = *(const short8*)&As[(wr * 64 + i * 16 + l16) * 64 + kk * 32 + lg * 8];
        bq[i] = *(const short8*)&Bs[(wc * 64 + i * 16 + l16) * 64 + kk * 32 + lg * 8];
      }
#pragma unroll
      for (int i = 0; i < 4; ++i)
#pragma unroll
        for (int j = 0; j < 4; ++j)
          acc[i][j] = __builtin_amdgcn_mfma_f32_16x16x32_bf16(af[i], bq[j], acc[i][j], 0, 0, 0);
    }
  }

  // ---- fused epilogue ----
  const int hg = bn * 2 + wc;   // global 64-wide head slot, uniform per wave
  if (hg >= 20) {               // V: cast + transposed store
    const int kvh = hg - 20;
#pragma unroll
    for (int i = 0; i < 4; ++i) {
      int row0 = bm * 128 + wr * 64 + i * 16 + lg * 4;
#pragma unroll
      for (int j = 0; j < 4; ++j) {
        int d = j * 16 + l16;
        ushort4 o = { f2bf(acc[i][j][0]), f2bf(acc[i][j][1]),
                      f2bf(acc[i][j][2]), f2bf(acc[i][j][3]) };
        *(ushort4*)(vtout + (size_t)(kvh * 64 + d) * S_LEN + row0) = o;
      }
    }
    return;
  }
  // Q/K: RMSNorm + RoPE
  const float* nw = (hg < 16) ? qw : kw;
  float wgt[4];
#pragma unroll
  for (int j = 0; j < 4; ++j) wgt[j] = nw[j * 16 + l16];
#pragma unroll
  for (int i = 0; i < 4; ++i) {
    int row0 = bm * 128 + wr * 64 + i * 16 + lg * 4;
    float qn[4][4];
#pragma unroll
    for (int r = 0; r < 4; ++r) {
      float ss = acc[i][0][r] * acc[i][0][r] + acc[i][1][r] * acc[i][1][r]
               + acc[i][2][r] * acc[i][2][r] + acc[i][3][r] * acc[i][3][r];
      ss += __shfl_xor(ss, 1);
      ss += __shfl_xor(ss, 2);
      ss += __shfl_xor(ss, 4);
      ss += __shfl_xor(ss, 8);
      float inv = rsqrtf(ss * (1.0f / 64.0f) + 1e-5f);
#pragma unroll
      for (int j = 0; j < 4; ++j) qn[j][r] = acc[i][j][r] * inv * wgt[j];
    }
#pragma unroll
    for (int j = 0; j < 4; ++j) {
      int d = j * 16 + l16;
#pragma unroll
      for (int r = 0; r < 4; ++r) {
        int row = row0 + r;
        float rot = (j < 2) ? -qn[j + 2][r] : qn[j - 2][r];   // rotate_half
        float o = qn[j][r] * cosb[row * 64 + d] + rot * sinb[row * 64 + d];
        if (hg < 16)
          qout[(size_t)row * HIDDEN + hg * 64 + d] = f2bf(o * QSCALE);
        else
          kout[((size_t)(hg - 16) * S_LEN + row) * 64 + d] = f2bf(o);
      }
    }
  }
}

// ---------------------------------------------------------------------------
// Kernel 4: C[M][N] = A[M][K] * B[N][K]^T (plain) — output projection.
// ---------------------------------------------------------------------------
__global__ __launch_bounds__(256) void k_gemm_bf16(
    const uint16_t* __restrict__ A, const uint16_t* __restrict__ B,
    float* __restrict__ C, int N, int K) {
  __shared__ uint16_t As[128 * 64];
  __shared__ uint16_t Bs[128 * 64];
  const int t = threadIdx.x;
  const int lane = t & 63, w = t >> 6;
  const int wr = w >> 1, wc = w & 1;
  const int l16 = lane & 15, lg = lane >> 4;
  const int bm = blockIdx.x, bn = blockIdx.y;
  const uint16_t* Ab = A + (size_t)bm * 128 * K;
  const uint16_t* Bb = B + (size_t)bn * 128 * K;
  f32x4 acc[4][4] = {};
  for (int k0 = 0; k0 < K; k0 += 64) {
    __syncthreads();
#pragma unroll
    for (int it = 0; it < 4; ++it) {
      int idx = it * 256 + t;
      int row = idx >> 3, c8 = (idx & 7) << 3;
      gld_lds16(&As[idx * 8], Ab + (size_t)row * K + k0 + c8);
      gld_lds16(&Bs[idx * 8], Bb + (size_t)row * K + k0 + c8);
    }
    __syncthreads();
#pragma unroll
    for (int kk = 0; kk < 2; ++kk) {
      short8 af[4], bq[4];
#pragma unroll
      for (int i = 0; i < 4; ++i) {
        af[i] = *(const short8*)&As[(wr * 64 + i * 16 + l16) * 64 + kk * 32 + lg * 8];
        bq[i] = *(const short8*)&Bs[(wc * 64 + i * 16 + l16) * 64 + kk * 32 + lg * 8];
      }
#pragma unroll
      for (int i = 0; i < 4; ++i)
#pragma unroll
        for (int j = 0; j < 4; ++j)
          acc[i][j] = __builtin_amdgcn_mfma_f32_16x16x32_bf16(af[i], bq[j], acc[i][j], 0, 0, 0);
    }
  }
#pragma unroll
  for (int i = 0; i < 4; ++i) {
    int row0 = bm * 128 + wr * 64 + i * 16 + lg * 4;
#pragma unroll
    for (int j = 0; j < 4; ++j) {
      int col = bn * 128 + wc * 64 + j * 16 + l16;
#pragma unroll
      for (int r = 0; r < 4; ++r)
        C[(size_t)(row0 + r) * N + col] = acc[i][j][r];
    }
  }
}

// ---------------------------------------------------------------------------
// Kernel 3: sliding-window flash attention, SWAPPED QK^T.
// Grid (S/64, 8), 512 threads = 8 waves. Block = one 64-row q-tile x two
// heads of one kv group. Wave w: head (w>>2), q-subtile (w&3).
// st[c] = mfma(K_frag, Q_frag): D[key][q] -> lane l16 owns ONE q-row;
// lsum is a per-lane scalar; P packed in-register -> 4x ds_write_b64/tile.
// Fixed-max softmax (|score*log2e| <= 8*L2E): p = exp2(s), no online max.
// ---------------------------------------------------------------------------
__global__ __launch_bounds__(512) void k_attn(
    const uint16_t* __restrict__ qb,   // [S][HIDDEN], pre-scaled by QSCALE
    const uint16_t* __restrict__ kb,   // [KV][S][64]
    const uint16_t* __restrict__ vtb,  // [KV][64][S]
    const float* __restrict__ sinks,
    uint16_t* __restrict__ ao) {       // [S][HIDDEN]
  __shared__ uint16_t Kl[64][72];      // +8 pad: 2-way-free on b128 reads
  __shared__ uint16_t Vl[64][72];      // V^T tile: [d][key]
  __shared__ uint16_t Pl[8][16][72];   // per-wave P: [q(16)][key(64)+pad]
  const int q0 = (63 - blockIdx.x) * 64;   // long blocks first
  const int hp = blockIdx.y;               // head-pair 0..7
  const int kvh = hp >> 1;
  const int t = threadIdx.x;
  const int lane = t & 63, w = t >> 6;
  const int h = kvh * 4 + (hp & 1) * 2 + (w >> 2);
  const int wq = w & 3;
  const int l16 = lane & 15, lg = lane >> 4;
  const int qrow = q0 + wq * 16 + l16;     // this lane's q-row (QK/softmax view)

  // Q fragment, used as the B operand (n = l16 = q-row)
  short8 bq0, bq1;
  {
    const uint16_t* qp = qb + (size_t)qrow * HIDDEN + h * 64 + lg * 8;
    bq0 = *(const short8*)qp;
    bq1 = *(const short8*)(qp + 32);
  }
  float lsum = 0.f;
  f32x4 acc[4] = {};

  int kstart = q0 - WINDOW;
  if (kstart < 0) kstart = 0;
  for (int k0 = kstart; k0 <= q0; k0 += 64) {
    __syncthreads();  // previous K/V tile fully consumed
    {   // stage K and V^T tiles: 512 threads -> one short8 each per array
      int row = t >> 3, c8 = (t & 7) << 3;
      *(short8*)&Kl[row][c8] =
          *(const short8*)(kb + ((size_t)kvh * S_LEN + k0 + row) * 64 + c8);
      *(short8*)&Vl[row][c8] =
          *(const short8*)(vtb + ((size_t)kvh * 64 + row) * S_LEN + k0 + c8);
    }
    __syncthreads();

    // S^T = K Q^T: D[m=key][n=q]. Same fragments as before, operands swapped.
    f32x4 st[4] = {};
#pragma unroll
    for (int c = 0; c < 4; ++c) {
      short8 ak0 = *(const short8*)&Kl[c * 16 + l16][lg * 8];
      short8 ak1 = *(const short8*)&Kl[c * 16 + l16][32 + lg * 8];
      st[c] = __builtin_amdgcn_mfma_f32_16x16x32_bf16(ak0, bq0, st[c], 0, 0, 0);
      st[c] = __builtin_amdgcn_mfma_f32_16x16x32_bf16(ak1, bq1, st[c], 0, 0, 0);
    }

    // key = k0 + c*16 + lg*4 + r; q-row = qrow (lane-local). Mask edge tiles only.
    float p[4][4];
    if (k0 == q0 || k0 == q0 - WINDOW) {
#pragma unroll
      for (int c = 0; c < 4; ++c) {
        int keyb = k0 + c * 16 + lg * 4;
#pragma unroll
        for (int r = 0; r < 4; ++r) {
          int key = keyb + r;
          bool ok = (key <= qrow) && (key + WINDOW > qrow);
          p[c][r] = ok ? exp2f(st[c][r]) : 0.f;
        }
      }
    } else {
#pragma unroll
      for (int c = 0; c < 4; ++c)
#pragma unroll
        for (int r = 0; r < 4; ++r)
          p[c][r] = exp2f(st[c][r]);
    }
#pragma unroll
    for (int c = 0; c < 4; ++c)
      lsum += (p[c][0] + p[c][1]) + (p[c][2] + p[c][3]);

    // pack P (keys consecutive in r) -> [q][key] LDS layout, 8B stores
#pragma unroll
    for (int c = 0; c < 4; ++c) {
      uint2 pw = { pk2(p[c][0], p[c][1]), pk2(p[c][2], p[c][3]) };
      *(uint2*)&Pl[w][l16][c * 16 + lg * 4] = pw;
    }
    asm volatile("s_waitcnt lgkmcnt(0)" ::: "memory");
    short8 pa0 = *(const short8*)&Pl[w][l16][lg * 8];
    short8 pa1 = *(const short8*)&Pl[w][l16][32 + lg * 8];
#pragma unroll
    for (int dt = 0; dt < 4; ++dt) {
      short8 bv0 = *(const short8*)&Vl[dt * 16 + l16][lg * 8];
      short8 bv1 = *(const short8*)&Vl[dt * 16 + l16][32 + lg * 8];
      acc[dt] = __builtin_amdgcn_mfma_f32_16x16x32_bf16(pa0, bv0, acc[dt], 0, 0, 0);
      acc[dt] = __builtin_amdgcn_mfma_f32_16x16x32_bf16(pa1, bv1, acc[dt], 0, 0, 0);
    }
  }

  // lsum: reduce across the 4 lg-groups (lanes sharing l16), add sink
  lsum += __shfl_xor(lsum, 16);
  lsum += __shfl_xor(lsum, 32);
  float sk = exp2f(sinks[h] * L2E);
  float inv = 1.0f / (lsum + sk);     // lane (l16,lg) holds inv for local row l16
  // acc rows are local row lg*4+r -> fetch inv from lane (lg*4+r)
#pragma unroll
  for (int r = 0; r < 4; ++r) {
    float rd = __shfl(inv, lg * 4 + r);
    int row = q0 + wq * 16 + lg * 4 + r;
#pragma unroll
    for (int dt = 0; dt < 4; ++dt)
      ao[(size_t)row * HIDDEN + h * 64 + dt * 16 + l16] = f2bf(acc[dt][r] * rd);
  }
}

// ---------------------------------------------------------------------------
// Launch. Workspace layout (~33 MB of d_ws):
//   [0,8M)    xb      bf16 x            [4096][1024]
//   [8,11M)   wqkvb   bf16 wq|wk|wv     [1536][1024]
//   [11,13M)  wob     bf16 wo           [1024][1024]
//   [13,21M)  qsc     bf16 q (scaled)   [4096][1024]
//   [21,23M)  kbf     bf16 k            [4][4096][64]
//   [23,25M)  vtb     bf16 v^T          [4][64][4096]
//   [25,33M)  aob     bf16 attn out     [4096][1024]
// ---------------------------------------------------------------------------
extern "C" void kernel_launch(void* const* d_in, const int* in_sizes, int n_in,
                              void* d_out, int out_size, void* d_ws, size_t ws_size,
                              hipStream_t stream) {
  const float* x     = (const float*)d_in[0];
  const float* cosb  = (const float*)d_in[1];
  const float* sinb  = (const float*)d_in[2];
  const float* wq    = (const float*)d_in[3];
  const float* wk    = (const float*)d_in[4];
  const float* wv    = (const float*)d_in[5];
  const float* wo    = (const float*)d_in[6];
  const float* qnw   = (const float*)d_in[7];
  const float* knw   = (const float*)d_in[8];
  const float* sinks = (const float*)d_in[9];
  float* out = (float*)d_out;

  char* ws = (char*)d_ws;
  uint16_t* xb    = (uint16_t*)(ws);
  uint16_t* wqkvb = (uint16_t*)(ws + (8ll  << 20));
  uint16_t* wob   = (uint16_t*)(ws + (11ll << 20));
  uint16_t* qsc   = (uint16_t*)(ws + (13ll << 20));
  uint16_t* kbf   = (uint16_t*)(ws + (21ll << 20));
  uint16_t* vtb   = (uint16_t*)(ws + (23ll << 20));
  uint16_t* aob   = (uint16_t*)(ws + (25ll << 20));

  k_tobf16  <<<6656, 256, 0, stream>>>(x, wq, wk, wv, wo, xb, wqkvb, wob);
  k_gemm_qkv<<<dim3(32, 12), 256, 0, stream>>>(xb, wqkvb, cosb, sinb, qnw, knw,
                                               qsc, kbf, vtb);
  k_attn    <<<dim3(64, 8), 512, 0, stream>>>(qsc, kbf, vtb, sinks, aob);
  k_gemm_bf16<<<dim3(32, 8), 256, 0, stream>>>(aob, wob, out, 1024, 1024);
}

// Round 4
// 83.098 us; speedup vs baseline: 1.4725x; 1.0877x over previous
//
#include <hip/hip_runtime.h>
#include <hip/hip_bf16.h>
#include <stdint.h>

// Problem constants
#define S_LEN   4096
#define HIDDEN  1024
#define NHEAD   16
#define NKV     4
#define HD      64
#define WINDOW  512
#define L2E     1.4426950408889634f
#define QSCALE  (0.125f * L2E)

using short8 = __attribute__((ext_vector_type(8))) short;
using f32x4  = __attribute__((ext_vector_type(4))) float;

// fp32 -> bf16, round-to-nearest-even
__device__ __forceinline__ uint16_t f2bf(float f) {
  uint32_t u = __builtin_bit_cast(uint32_t, f);
  u += 0x7fffu + ((u >> 16) & 1u);
  return (uint16_t)(u >> 16);
}
// round-to-nearest (ties up) — P values only (all >=0, bias ~2^-17)
__device__ __forceinline__ uint16_t f2bf_rn(float f) {
  uint32_t u = __builtin_bit_cast(uint32_t, f);
  return (uint16_t)((u + 0x8000u) >> 16);
}
__device__ __forceinline__ uint32_t pk2(float a, float b) {
  return (uint32_t)f2bf_rn(a) | ((uint32_t)f2bf_rn(b) << 16);
}

// async global->LDS, 16B per lane. LDS dest must be wave-uniform base + lane*16.
__device__ __forceinline__ void gld_lds16(void* lds, const void* g) {
  __builtin_amdgcn_global_load_lds(
      (const __attribute__((address_space(1))) char*)g,
      (__attribute__((address_space(3))) char*)lds, 16, 0, 0);
}

// ---------------------------------------------------------------------------
// Kernel 1: pack x, wq|wk|wv (concat rows), wo to bf16
// ---------------------------------------------------------------------------
__global__ __launch_bounds__(256) void k_tobf16(
    const float* __restrict__ x, const float* __restrict__ wq,
    const float* __restrict__ wk, const float* __restrict__ wv,
    const float* __restrict__ wo,
    uint16_t* __restrict__ xb, uint16_t* __restrict__ wqkvb,
    uint16_t* __restrict__ wob) {
  int i = blockIdx.x * 256 + threadIdx.x;  // one float4 per thread, exact grid
  const float4* src; uint16_t* dst; int off;
  if (i < 1048576)      { src = (const float4*)x;  dst = xb;                off = i; }
  else if (i < 1310720) { src = (const float4*)wq; dst = wqkvb;             off = i - 1048576; }
  else if (i < 1376256) { src = (const float4*)wk; dst = wqkvb + 1024*1024; off = i - 1310720; }
  else if (i < 1441792) { src = (const float4*)wv; dst = wqkvb + 1280*1024; off = i - 1376256; }
  else                  { src = (const float4*)wo; dst = wob;               off = i - 1441792; }
  float4 v = src[off];
  ushort4 o = { f2bf(v.x), f2bf(v.y), f2bf(v.z), f2bf(v.w) };
  *(ushort4*)(dst + (size_t)off * 4) = o;
}

// ---------------------------------------------------------------------------
// Kernel 2: QKV GEMM with fused RMSNorm + RoPE + cast + layout epilogue.
// BM=64, BN=128, BK=64; 4 waves in 2x2, wave tile 32x64 (acc[2][4]).
// Grid (64, 12) = 768 blocks = exactly 3 blocks/CU (balanced, 12 waves/CU).
// Each wave's 64-col half-tile is exactly ONE head (hg = bn*2+wc):
//   [0,16) q-head -> norm+rope, * QSCALE, qout[s][hg*64+d]
//   [16,20) k-head -> norm+rope, kout[kv][s][d]
//   [20,24) v-head -> cast, vtout[kv][d][s] (8B vector stores)
// ---------------------------------------------------------------------------
__global__ __launch_bounds__(256) void k_gemm_qkv(
    const uint16_t* __restrict__ A, const uint16_t* __restrict__ B,
    const float* __restrict__ cosb, const float* __restrict__ sinb,
    const float* __restrict__ qw, const float* __restrict__ kw,
    uint16_t* __restrict__ qout, uint16_t* __restrict__ kout,
    uint16_t* __restrict__ vtout) {
  __shared__ uint16_t As[64 * 64];
  __shared__ uint16_t Bs[128 * 64];
  const int K = 1024;
  const int t = threadIdx.x;
  const int lane = t & 63, w = t >> 6;
  const int wr = w >> 1, wc = w & 1;
  const int l16 = lane & 15, lg = lane >> 4;
  const int bm = blockIdx.x, bn = blockIdx.y;
  const uint16_t* Ab = A + (size_t)bm * 64 * K;
  const uint16_t* Bb = B + (size_t)bn * 128 * K;
  f32x4 acc[2][4] = {};
  for (int k0 = 0; k0 < K; k0 += 64) {
    __syncthreads();
    {  // stage A: 64x64 = 512 16B-chunks -> 2/thread
      int row = t >> 3, c8 = (t & 7) << 3;
      gld_lds16(&As[t * 8], Ab + (size_t)row * K + k0 + c8);
      int t2 = t + 256, row2 = t2 >> 3, c82 = (t2 & 7) << 3;
      gld_lds16(&As[t2 * 8], Ab + (size_t)row2 * K + k0 + c82);
    }
#pragma unroll
    for (int it = 0; it < 4; ++it) {  // stage B: 128x64 -> 4/thread
      int idx = it * 256 + t;
      int row = idx >> 3, c8 = (idx & 7) << 3;
      gld_lds16(&Bs[idx * 8], Bb + (size_t)row * K + k0 + c8);
    }
    __syncthreads();
#pragma unroll
    for (int kk = 0; kk < 2; ++kk) {
      short8 af[2], bq[4];
#pragma unroll
      for (int i = 0; i < 2; ++i)
        af[i] = *(const short8*)&As[(wr * 32 + i * 16 + l16) * 64 + kk * 32 + lg * 8];
#pragma unroll
      for (int j = 0; j < 4; ++j)
        bq[j] = *(const short8*)&Bs[(wc * 64 + j * 16 + l16) * 64 + kk * 32 + lg * 8];
#pragma unroll
      for (int i = 0; i < 2; ++i)
#pragma unroll
        for (int j = 0; j < 4; ++j)
          acc[i][j] = __builtin_amdgcn_mfma_f32_16x16x32_bf16(af[i], bq[j], acc[i][j], 0, 0, 0);
    }
  }

  // ---- fused epilogue ----
  const int hg = bn * 2 + wc;   // global 64-wide head slot, uniform per wave
  if (hg >= 20) {               // V: cast + transposed store
    const int kvh = hg - 20;
#pragma unroll
    for (int i = 0; i < 2; ++i) {
      int row0 = bm * 64 + wr * 32 + i * 16 + lg * 4;
#pragma unroll
      for (int j = 0; j < 4; ++j) {
        int d = j * 16 + l16;
        ushort4 o = { f2bf(acc[i][j][0]), f2bf(acc[i][j][1]),
                      f2bf(acc[i][j][2]), f2bf(acc[i][j][3]) };
        *(ushort4*)(vtout + (size_t)(kvh * 64 + d) * S_LEN + row0) = o;
      }
    }
    return;
  }
  // Q/K: RMSNorm + RoPE
  const float* nw = (hg < 16) ? qw : kw;
  float wgt[4];
#pragma unroll
  for (int j = 0; j < 4; ++j) wgt[j] = nw[j * 16 + l16];
#pragma unroll
  for (int i = 0; i < 2; ++i) {
    int row0 = bm * 64 + wr * 32 + i * 16 + lg * 4;
    float qn[4][4];
#pragma unroll
    for (int r = 0; r < 4; ++r) {
      float ss = acc[i][0][r] * acc[i][0][r] + acc[i][1][r] * acc[i][1][r]
               + acc[i][2][r] * acc[i][2][r] + acc[i][3][r] * acc[i][3][r];
      ss += __shfl_xor(ss, 1);
      ss += __shfl_xor(ss, 2);
      ss += __shfl_xor(ss, 4);
      ss += __shfl_xor(ss, 8);
      float inv = rsqrtf(ss * (1.0f / 64.0f) + 1e-5f);
#pragma unroll
      for (int j = 0; j < 4; ++j) qn[j][r] = acc[i][j][r] * inv * wgt[j];
    }
#pragma unroll
    for (int j = 0; j < 4; ++j) {
      int d = j * 16 + l16;
#pragma unroll
      for (int r = 0; r < 4; ++r) {
        int row = row0 + r;
        float rot = (j < 2) ? -qn[j + 2][r] : qn[j - 2][r];   // rotate_half
        float o = qn[j][r] * cosb[row * 64 + d] + rot * sinb[row * 64 + d];
        if (hg < 16)
          qout[(size_t)row * HIDDEN + hg * 64 + d] = f2bf(o * QSCALE);
        else
          kout[((size_t)(hg - 16) * S_LEN + row) * 64 + d] = f2bf(o);
      }
    }
  }
}

// ---------------------------------------------------------------------------
// Kernel 4: C[M][N] = A[M][K] * B[N][K]^T — output projection.
// Same 64x128 geometry: grid (64, 8) = 512 blocks = 2/CU balanced.
// ---------------------------------------------------------------------------
__global__ __launch_bounds__(256) void k_gemm_bf16(
    const uint16_t* __restrict__ A, const uint16_t* __restrict__ B,
    float* __restrict__ C, int N, int K) {
  __shared__ uint16_t As[64 * 64];
  __shared__ uint16_t Bs[128 * 64];
  const int t = threadIdx.x;
  const int lane = t & 63, w = t >> 6;
  const int wr = w >> 1, wc = w & 1;
  const int l16 = lane & 15, lg = lane >> 4;
  const int bm = blockIdx.x, bn = blockIdx.y;
  const uint16_t* Ab = A + (size_t)bm * 64 * K;
  const uint16_t* Bb = B + (size_t)bn * 128 * K;
  f32x4 acc[2][4] = {};
  for (int k0 = 0; k0 < K; k0 += 64) {
    __syncthreads();
    {
      int row = t >> 3, c8 = (t & 7) << 3;
      gld_lds16(&As[t * 8], Ab + (size_t)row * K + k0 + c8);
      int t2 = t + 256, row2 = t2 >> 3, c82 = (t2 & 7) << 3;
      gld_lds16(&As[t2 * 8], Ab + (size_t)row2 * K + k0 + c82);
    }
#pragma unroll
    for (int it = 0; it < 4; ++it) {
      int idx = it * 256 + t;
      int row = idx >> 3, c8 = (idx & 7) << 3;
      gld_lds16(&Bs[idx * 8], Bb + (size_t)row * K + k0 + c8);
    }
    __syncthreads();
#pragma unroll
    for (int kk = 0; kk < 2; ++kk) {
      short8 af[2], bq[4];
#pragma unroll
      for (int i = 0; i < 2; ++i)
        af[i] = *(const short8*)&As[(wr * 32 + i * 16 + l16) * 64 + kk * 32 + lg * 8];
#pragma unroll
      for (int j = 0; j < 4; ++j)
        bq[j] = *(const short8*)&Bs[(wc * 64 + j * 16 + l16) * 64 + kk * 32 + lg * 8];
#pragma unroll
      for (int i = 0; i < 2; ++i)
#pragma unroll
        for (int j = 0; j < 4; ++j)
          acc[i][j] = __builtin_amdgcn_mfma_f32_16x16x32_bf16(af[i], bq[j], acc[i][j], 0, 0, 0);
    }
  }
#pragma unroll
  for (int i = 0; i < 2; ++i) {
    int row0 = bm * 64 + wr * 32 + i * 16 + lg * 4;
#pragma unroll
    for (int j = 0; j < 4; ++j) {
      int col = bn * 128 + wc * 64 + j * 16 + l16;
#pragma unroll
      for (int r = 0; r < 4; ++r)
        C[(size_t)(row0 + r) * N + col] = acc[i][j][r];
    }
  }
}

// ---------------------------------------------------------------------------
// Kernel 3: sliding-window flash attention, SWAPPED QK^T.
// Grid (S/64, 8), 512 threads = 8 waves. Block = one 64-row q-tile x two
// heads of one kv group. Wave w: head (w>>2), q-subtile (w&3).
// st[c] = mfma(K_frag, Q_frag): D[key][q] -> lane l16 owns ONE q-row;
// lsum is a per-lane scalar; P packed in-register -> 4x ds_write_b64/tile.
// Fixed-max softmax (scores bounded by RMSNorm): p = exp2(s), no online max.
// ---------------------------------------------------------------------------
__global__ __launch_bounds__(512) void k_attn(
    const uint16_t* __restrict__ qb,   // [S][HIDDEN], pre-scaled by QSCALE
    const uint16_t* __restrict__ kb,   // [KV][S][64]
    const uint16_t* __restrict__ vtb,  // [KV][64][S]
    const float* __restrict__ sinks,
    uint16_t* __restrict__ ao) {       // [S][HIDDEN]
  __shared__ uint16_t Kl[64][72];      // +8 pad: 2-way-free on b128 reads
  __shared__ uint16_t Vl[64][72];      // V^T tile: [d][key]
  __shared__ uint16_t Pl[8][16][72];   // per-wave P: [q(16)][key(64)+pad]
  const int q0 = (63 - blockIdx.x) * 64;   // long blocks first
  const int hp = blockIdx.y;               // head-pair 0..7
  const int kvh = hp >> 1;
  const int t = threadIdx.x;
  const int lane = t & 63, w = t >> 6;
  const int h = kvh * 4 + (hp & 1) * 2 + (w >> 2);
  const int wq = w & 3;
  const int l16 = lane & 15, lg = lane >> 4;
  const int qrow = q0 + wq * 16 + l16;     // this lane's q-row (QK/softmax view)

  // Q fragment, used as the B operand (n = l16 = q-row)
  short8 bq0, bq1;
  {
    const uint16_t* qp = qb + (size_t)qrow * HIDDEN + h * 64 + lg * 8;
    bq0 = *(const short8*)qp;
    bq1 = *(const short8*)(qp + 32);
  }
  float lsum = 0.f;
  f32x4 acc[4] = {};

  int kstart = q0 - WINDOW;
  if (kstart < 0) kstart = 0;
  for (int k0 = kstart; k0 <= q0; k0 += 64) {
    __syncthreads();  // previous K/V tile fully consumed
    {   // stage K and V^T tiles: 512 threads -> one short8 each per array
      int row = t >> 3, c8 = (t & 7) << 3;
      *(short8*)&Kl[row][c8] =
          *(const short8*)(kb + ((size_t)kvh * S_LEN + k0 + row) * 64 + c8);
      *(short8*)&Vl[row][c8] =
          *(const short8*)(vtb + ((size_t)kvh * 64 + row) * S_LEN + k0 + c8);
    }
    __syncthreads();

    // S^T = K Q^T: D[m=key][n=q].
    f32x4 st[4] = {};
#pragma unroll
    for (int c = 0; c < 4; ++c) {
      short8 ak0 = *(const short8*)&Kl[c * 16 + l16][lg * 8];
      short8 ak1 = *(const short8*)&Kl[c * 16 + l16][32 + lg * 8];
      st[c] = __builtin_amdgcn_mfma_f32_16x16x32_bf16(ak0, bq0, st[c], 0, 0, 0);
      st[c] = __builtin_amdgcn_mfma_f32_16x16x32_bf16(ak1, bq1, st[c], 0, 0, 0);
    }

    // key = k0 + c*16 + lg*4 + r; q-row = qrow (lane-local). Mask edge tiles only.
    float p[4][4];
    if (k0 == q0 || k0 == q0 - WINDOW) {
#pragma unroll
      for (int c = 0; c < 4; ++c) {
        int keyb = k0 + c * 16 + lg * 4;
#pragma unroll
        for (int r = 0; r < 4; ++r) {
          int key = keyb + r;
          bool ok = (key <= qrow) && (key + WINDOW > qrow);
          p[c][r] = ok ? exp2f(st[c][r]) : 0.f;
        }
      }
    } else {
#pragma unroll
      for (int c = 0; c < 4; ++c)
#pragma unroll
        for (int r = 0; r < 4; ++r)
          p[c][r] = exp2f(st[c][r]);
    }
#pragma unroll
    for (int c = 0; c < 4; ++c)
      lsum += (p[c][0] + p[c][1]) + (p[c][2] + p[c][3]);

    // pack P (keys consecutive in r) -> [q][key] LDS layout, 8B stores
#pragma unroll
    for (int c = 0; c < 4; ++c) {
      uint2 pw = { pk2(p[c][0], p[c][1]), pk2(p[c][2], p[c][3]) };
      *(uint2*)&Pl[w][l16][c * 16 + lg * 4] = pw;
    }
    asm volatile("s_waitcnt lgkmcnt(0)" ::: "memory");
    short8 pa0 = *(const short8*)&Pl[w][l16][lg * 8];
    short8 pa1 = *(const short8*)&Pl[w][l16][32 + lg * 8];
#pragma unroll
    for (int dt = 0; dt < 4; ++dt) {
      short8 bv0 = *(const short8*)&Vl[dt * 16 + l16][lg * 8];
      short8 bv1 = *(const short8*)&Vl[dt * 16 + l16][32 + lg * 8];
      acc[dt] = __builtin_amdgcn_mfma_f32_16x16x32_bf16(pa0, bv0, acc[dt], 0, 0, 0);
      acc[dt] = __builtin_amdgcn_mfma_f32_16x16x32_bf16(pa1, bv1, acc[dt], 0, 0, 0);
    }
  }

  // lsum: reduce across the 4 lg-groups (lanes sharing l16), add sink
  lsum += __shfl_xor(lsum, 16);
  lsum += __shfl_xor(lsum, 32);
  float sk = exp2f(sinks[h] * L2E);
  float inv = 1.0f / (lsum + sk);     // lane (l16,lg) holds inv for local row l16
  // acc rows are local row lg*4+r -> fetch inv from lane (lg*4+r)
#pragma unroll
  for (int r = 0; r < 4; ++r) {
    float rd = __shfl(inv, lg * 4 + r);
    int row = q0 + wq * 16 + lg * 4 + r;
#pragma unroll
    for (int dt = 0; dt < 4; ++dt)
      ao[(size_t)row * HIDDEN + h * 64 + dt * 16 + l16] = f2bf(acc[dt][r] * rd);
  }
}

// ---------------------------------------------------------------------------
// Launch. Workspace layout (~33 MB of d_ws):
//   [0,8M)    xb      bf16 x            [4096][1024]
//   [8,11M)   wqkvb   bf16 wq|wk|wv     [1536][1024]
//   [11,13M)  wob     bf16 wo           [1024][1024]
//   [13,21M)  qsc     bf16 q (scaled)   [4096][1024]
//   [21,23M)  kbf     bf16 k            [4][4096][64]
//   [23,25M)  vtb     bf16 v^T          [4][64][4096]
//   [25,33M)  aob     bf16 attn out     [4096][1024]
// ---------------------------------------------------------------------------
extern "C" void kernel_launch(void* const* d_in, const int* in_sizes, int n_in,
                              void* d_out, int out_size, void* d_ws, size_t ws_size,
                              hipStream_t stream) {
  const float* x     = (const float*)d_in[0];
  const float* cosb  = (const float*)d_in[1];
  const float* sinb  = (const float*)d_in[2];
  const float* wq    = (const float*)d_in[3];
  const float* wk    = (const float*)d_in[4];
  const float* wv    = (const float*)d_in[5];
  const float* wo    = (const float*)d_in[6];
  const float* qnw   = (const float*)d_in[7];
  const float* knw   = (const float*)d_in[8];
  const float* sinks = (const float*)d_in[9];
  float* out = (float*)d_out;

  char* ws = (char*)d_ws;
  uint16_t* xb    = (uint16_t*)(ws);
  uint16_t* wqkvb = (uint16_t*)(ws + (8ll  << 20));
  uint16_t* wob   = (uint16_t*)(ws + (11ll << 20));
  uint16_t* qsc   = (uint16_t*)(ws + (13ll << 20));
  uint16_t* kbf   = (uint16_t*)(ws + (21ll << 20));
  uint16_t* vtb   = (uint16_t*)(ws + (23ll << 20));
  uint16_t* aob   = (uint16_t*)(ws + (25ll << 20));

  k_tobf16  <<<6656, 256, 0, stream>>>(x, wq, wk, wv, wo, xb, wqkvb, wob);
  k_gemm_qkv<<<dim3(64, 12), 256, 0, stream>>>(xb, wqkvb, cosb, sinb, qnw, knw,
                                               qsc, kbf, vtb);
  k_attn    <<<dim3(64, 8), 512, 0, stream>>>(qsc, kbf, vtb, sinks, aob);
  k_gemm_bf16<<<dim3(64, 8), 256, 0, stream>>>(aob, wob, out, 1024, 1024);
}